// Round 8
// baseline (242.724 us; speedup 1.0000x reference)
//
#include <hip/hip_runtime.h>

#define BATCH 16
#define CIN   256
#define NSP   4096
#define HID   512

typedef short v8s __attribute__((ext_vector_type(8)));
typedef float v4f __attribute__((ext_vector_type(4)));

__device__ __forceinline__ unsigned short f2bf(float f) {
    union { float f; unsigned u; } a; a.f = f;
    unsigned r = a.u + 0x7fffu + ((a.u >> 16) & 1u);
    return (unsigned short)(r >> 16);
}

__device__ __forceinline__ void gld_lds16(const unsigned short* g, unsigned short* l) {
    __builtin_amdgcn_global_load_lds(
        (const __attribute__((address_space(1))) unsigned int*)g,
        (__attribute__((address_space(3))) unsigned int*)l,
        16, 0, 0);
}

// Swizzled [rows][64] bf16 LDS tile: slot s (8 shorts) of row r stored at slot (s+r)&7.
// Staging lane (srow8=lane>>3, sslot=lane&7) loads global col ((sslot-srow8)&7)*8.
// Reader of (row r, k-half h): LDS col = ((quad + r)&7)*8 ^ (h*32).  0 conflicts (R7 PMC).

// ---------------- P: weights prep + x prep + zacc zero (merged) ---------------------
__global__ __launch_bounds__(256) void k_prep(const float* __restrict__ x,
                                              const float* __restrict__ wq,
                                              unsigned short* __restrict__ xbf,
                                              unsigned short* __restrict__ xT,
                                              unsigned short* __restrict__ wbf,
                                              unsigned short* __restrict__ wqT,
                                              float* __restrict__ zacc) {
    const int bid = blockIdx.x;
    const int t = threadIdx.x;
    if (bid >= 4320) {                        // 32 blocks: zero zacc (16x512 fp32)
        zacc[(bid - 4320) * 256 + t] = 0.f;
        return;
    }
    if (bid >= 4096) {
        const int wid = bid - 4096;
        if (wid < 192) {                      // bf16 convert of full w_qkv
            const int g = wid * 256 + t;
            const float4 f0 = *(const float4*)(wq + (size_t)g * 8);
            const float4 f1 = *(const float4*)(wq + (size_t)g * 8 + 4);
            union { unsigned short s[8]; uint4 u; } p;
            p.s[0] = f2bf(f0.x); p.s[1] = f2bf(f0.y); p.s[2] = f2bf(f0.z); p.s[3] = f2bf(f0.w);
            p.s[4] = f2bf(f1.x); p.s[5] = f2bf(f1.y); p.s[6] = f2bf(f1.z); p.s[7] = f2bf(f1.w);
            *(uint4*)(wbf + (size_t)g * 8) = p.u;
            return;
        }
        __shared__ float tile[64 * 65];       // 32 blocks: wqT transpose (q part)
        const int bb = wid - 192;
        const int u0 = (bb & 7) * 64, c0 = (bb >> 3) * 64;
        {
            const int cl = (t & 15) * 4, ul = t >> 4;
            #pragma unroll
            for (int i = 0; i < 4; i++) {
                int u = ul + i * 16;
                const float4 f = *(const float4*)(wq + (size_t)(u0 + u) * CIN + c0 + cl);
                *(float4*)(&tile[u * 65 + cl]) = f;
            }
        }
        __syncthreads();
        {
            const int ul4 = (t & 15) * 4, cl = t >> 4;
            #pragma unroll
            for (int i = 0; i < 4; i++) {
                int c = cl + i * 16;
                union { unsigned short s[4]; uint2 u; } p;
                #pragma unroll
                for (int j = 0; j < 4; j++)
                    p.s[j] = f2bf(tile[(ul4 + j) * 65 + c]);
                *(uint2*)(wqT + (size_t)(c0 + c) * HID + u0 + ul4) = p.u;
            }
        }
        return;
    }
    // x prep: 4096 blocks of 64x64 tiles
    __shared__ float tile[64 * 65];
    const int n0 = (bid & 63) * 64, c0 = ((bid >> 6) & 3) * 64, bz = bid >> 8;
    const float* xb = x + (size_t)bz * CIN * NSP;
    {
        const int nl = (t & 15) * 4, cl = t >> 4;
        #pragma unroll
        for (int i = 0; i < 4; i++) {
            int c = cl + i * 16;
            const float4 f = *(const float4*)(xb + (size_t)(c0 + c) * NSP + n0 + nl);
            *(float4*)(&tile[c * 65 + nl]) = f;
            union { unsigned short s[4]; uint2 u; } p;
            p.s[0] = f2bf(f.x); p.s[1] = f2bf(f.y); p.s[2] = f2bf(f.z); p.s[3] = f2bf(f.w);
            *(uint2*)(xbf + ((size_t)bz * CIN + c0 + c) * NSP + n0 + nl) = p.u;
        }
    }
    __syncthreads();
    {
        const int cl4 = (t & 15) * 4, nl = t >> 4;
        #pragma unroll
        for (int i = 0; i < 4; i++) {
            int n = nl + i * 16;
            union { unsigned short s[4]; uint2 u; } p;
            #pragma unroll
            for (int j = 0; j < 4; j++)
                p.s[j] = f2bf(tile[(cl4 + j) * 65 + n]);
            *(uint2*)(xT + ((size_t)bz * NSP + n0 + n) * CIN + c0 + cl4) = p.u;
        }
    }
}

// ---------------- KS: fused  E = exp(Wk @ x)  and  S += xbf @ E^T  ------------------
// v8 = T3/T4 counted-vmcnt schedule. R1-R7: every variant with __syncthreads()
// (= vmcnt(0) drain x32/block) lands at 48-54us with ~50% no-issue cycles.
// Now: A1/A2/Es all double-buffered (144 KB, 1 blk/CU); raw s_barrier; loads
// issued at iter top get a full iteration before their counted wait:
//   top: STAGE_A2(nt)[4] ; STAGE_A1(nt+1)[4]
//   vmcnt(8)  -> prev iter's 8 loads done (A1(nt) ready) ; s_barrier
//   G1 (A1[buf] x Wk-reg) ; exp -> Es[nt&1]
//   lgkmcnt(0) ; s_barrier
//   vmcnt(4)  -> A2(nt) ready (A1(nt+1) stays in flight)
//   G2 (A2[nt&1] x Es[nt&1])
// Hazards: each WAR/RAW pair separated by >=1 barrier + buffer parity (checked).
// MFMA inputs/order bit-identical to R6.
__global__ __launch_bounds__(512, 1) void k_ks(const unsigned short* __restrict__ wbf,
                                               const unsigned short* __restrict__ xT,
                                               const unsigned short* __restrict__ xbf,
                                               float* __restrict__ Sp,
                                               float* __restrict__ zacc) {
    __shared__ __align__(16) unsigned short A1s[2][4][64][64]; // 64 KB: [buf][kk][n][64k]
    __shared__ __align__(16) unsigned short A2s[2][256][64];   // 64 KB: [buf][c][64n]
    __shared__ __align__(16) unsigned short Es[2][64][64];     // 16 KB: [buf][d][n]

    const int t = threadIdx.x;
    const int id = blockIdx.x;
    const int bz = id & 15, dblk = (id >> 4) & 7, nc = id >> 7;
    const int d0 = dblk * 64;
    const int nbase = nc * 1024;
    const int lane = t & 63, wv = t >> 6, quad = lane >> 4, l15 = lane & 15;
    const int srow8 = lane >> 3, sslot = lane & 7;
    const int scol = ((sslot - srow8) & 7) * 8;
    const int sw0 = ((quad + l15) & 7) * 8;
    // G1 roles: wn = n-strip (16 rows), wd = d-half (32)
    const int wn = wv & 3, wd = wv >> 2;

    auto STAGE_A1 = [&](int buf, int n0s) {
        #pragma unroll
        for (int i = 0; i < 4; i++) {
            const int flat = wv * 4 + i;          // 0..31
            const int kl = flat >> 3, rb = flat & 7;
            gld_lds16(xT + ((size_t)bz * NSP + n0s + rb * 8 + srow8) * CIN + kl * 64 + scol,
                      &A1s[buf][kl][rb * 8][0]);
        }
    };
    auto STAGE_A2 = [&](int buf, int n0s) {
        #pragma unroll
        for (int i = 0; i < 4; i++) {
            const int rb = wv * 4 + i;            // 0..31
            gld_lds16(xbf + ((size_t)bz * CIN + rb * 8 + srow8) * NSP + n0s + scol,
                      &A2s[buf][rb * 8][0]);
        }
    };

    // ---- prologue: stage Wk into A2s[0], hoist frags (full drain ok, once) ---------
    {
        #pragma unroll
        for (int i = 0; i < 4; i++) {
            const int flat = wv * 4 + i;          // 0..31
            const int kk = flat >> 3, rb = flat & 7;
            gld_lds16(wbf + (size_t)(512 + d0 + rb * 8 + srow8) * CIN + kk * 64 + scol,
                      &A2s[0][0][0] + (kk * 64 + rb * 8) * 64);
        }
    }
    __syncthreads();
    v8s Wkf[4][2][2];                             // [kk][ni (16-d of my half)][h]
    #pragma unroll
    for (int kk = 0; kk < 4; kk++)
        #pragma unroll
        for (int ni = 0; ni < 2; ni++)
            #pragma unroll
            for (int h = 0; h < 2; h++) {
                union { v8s v; uint4 u; } rr;
                rr.u = *(const uint4*)(&A2s[0][0][0] +
                        (size_t)(kk * 64 + wd * 32 + ni * 16 + l15) * 64 + (sw0 ^ (h * 32)));
                Wkf[kk][ni][h] = rr.v;
            }
    __syncthreads();

    v4f acc2[2][4];                               // S partial [c 32/wave][d 64]
    #pragma unroll
    for (int i = 0; i < 2; i++)
        #pragma unroll
        for (int j = 0; j < 4; j++) acc2[i][j] = (v4f)0.f;
    float za[2] = {0.f, 0.f};

    STAGE_A1(0, nbase);                           // A1(0) -> buf0   [4 in flight]

    int buf = 0;
    for (int nt = 0; nt < 16; nt++) {
        const int n0s = nbase + nt * 64;
        // issue this iter's loads first (they wait a full iteration)
        STAGE_A2(nt & 1, n0s);                                  // +4
        const int n1 = (nt < 15) ? (n0s + 64) : nbase;          // clamp: uniform count
        STAGE_A1(buf ^ 1, n1);                                  // +4 (never read at nt=15)

        // A1(nt) = the 8-back cohort -> counted wait, no drain
        asm volatile("s_waitcnt vmcnt(8)" ::: "memory");
        __builtin_amdgcn_s_barrier();             // all waves' A1(nt) visible

        // G1: wave owns n-rows [wn*16,+16), d-half [wd*32,+32)
        v4f acc1[2];
        acc1[0] = (v4f)0.f; acc1[1] = (v4f)0.f;

        __builtin_amdgcn_s_setprio(1);
        #pragma unroll
        for (int kk = 0; kk < 4; kk++) {
            #pragma unroll
            for (int h = 0; h < 2; h++) {
                union { v8s v; uint4 u; } rr;
                rr.u = *(const uint4*)(&A1s[buf][kk][wn * 16 + l15][0] + (sw0 ^ (h * 32)));
                const v8s af = rr.v;
                #pragma unroll
                for (int ni = 0; ni < 2; ni++)
                    acc1[ni] = __builtin_amdgcn_mfma_f32_16x16x32_bf16(af, Wkf[kk][ni][h], acc1[ni], 0, 0, 0);
            }
        }
        __builtin_amdgcn_s_setprio(0);

        // E epilogue: exp, z accumulate, write Es[nt&1] (slot-rotated)
        #pragma unroll
        for (int ni = 0; ni < 2; ni++) {
            const int d = wd * 32 + ni * 16 + l15;
            union { unsigned short s[4]; uint2 u; } p;
            #pragma unroll
            for (int rr = 0; rr < 4; rr++) {
                float e = __expf(acc1[ni][rr]);
                za[ni] += e;
                p.s[rr] = f2bf(e);
            }
            const int slot = (wn * 2 + (quad >> 1) + d) & 7;
            *(uint2*)(&Es[nt & 1][d][slot * 8 + (quad & 1) * 4]) = p.u;
        }
        asm volatile("s_waitcnt lgkmcnt(0)" ::: "memory");
        __builtin_amdgcn_s_barrier();             // Es[nt&1] visible to all waves

        // A2(nt) = oldest 4 of the 8 in flight -> counted wait
        asm volatile("s_waitcnt vmcnt(4)" ::: "memory");

        __builtin_amdgcn_s_setprio(1);
        #pragma unroll
        for (int kst = 0; kst < 2; kst++) {
            const int esw = sw0 ^ (kst * 32);
            v8s af[2], bfr[4];
            #pragma unroll
            for (int mi = 0; mi < 2; mi++) {
                union { v8s v; uint4 u; } rr;
                rr.u = *(const uint4*)(&A2s[nt & 1][wv * 32 + mi * 16 + l15][0] + esw);
                af[mi] = rr.v;
            }
            #pragma unroll
            for (int ni = 0; ni < 4; ni++) {
                union { v8s v; uint4 u; } rr;
                rr.u = *(const uint4*)(&Es[nt & 1][ni * 16 + l15][0] + esw);
                bfr[ni] = rr.v;
            }
            #pragma unroll
            for (int mi = 0; mi < 2; mi++)
                #pragma unroll
                for (int ni = 0; ni < 4; ni++)
                    acc2[mi][ni] = __builtin_amdgcn_mfma_f32_16x16x32_bf16(af[mi], bfr[ni], acc2[mi][ni], 0, 0, 0);
        }
        __builtin_amdgcn_s_setprio(0);
        buf ^= 1;
    }

    // z: reduce across quads; 4 wn-sibling waves atomically add each (d) - ok
    #pragma unroll
    for (int ni = 0; ni < 2; ni++) {
        float z = za[ni];
        z += __shfl_xor(z, 16);
        z += __shfl_xor(z, 32);
        if (quad == 0)
            atomicAdd(&zacc[bz * 512 + d0 + wd * 32 + ni * 16 + l15], z);
    }

    // Sp store: slice ((bh*2+ch)*4 + nc), [128 d][128 c] fp32; this block owns the
    // (dblk&1)*64 d-half (sibling dblk^1 owns the other) -> disjoint, k_sred unchanged.
    const int bh = bz * 4 + (dblk >> 1);
    const int ch = wv >> 2;
    float* outp = Sp + ((size_t)(bh * 2 + ch) * 4 + nc) * 16384;
    #pragma unroll
    for (int ni = 0; ni < 4; ni++) {
        const int dl = (dblk & 1) * 64 + ni * 16 + l15;
        #pragma unroll
        for (int mi = 0; mi < 2; mi++) {
            const int cl = (wv & 3) * 32 + mi * 16 + quad * 4;
            *(v4f*)(outp + dl * 128 + cl) = acc2[mi][ni];
        }
    }
}

// ---------------- K3: reduce S partials -> Sred bf16 [bh][128 d][256 c] -------------
__global__ __launch_bounds__(256) void k_sred(const float* __restrict__ Sp,
                                              unsigned short* __restrict__ Sred) {
    const int qv = blockIdx.x * 256 + threadIdx.x;   // 524288 quads
    const int bh = qv >> 13, r = qv & 8191;
    const int dl = r >> 6, cq6 = r & 63;
    const int ch = cq6 >> 5, clq = cq6 & 31;
    const float* p = Sp + ((size_t)(bh * 2 + ch) * 4) * 16384 + dl * 128 + clq * 4;
    float4 s = *(const float4*)p;
    #pragma unroll
    for (int kc = 1; kc < 4; kc++) {
        const float4 f = *(const float4*)(p + (size_t)kc * 16384);
        s.x += f.x; s.y += f.y; s.z += f.z; s.w += f.w;
    }
    union { unsigned short us[4]; uint2 u; } pk;
    pk.us[0] = f2bf(s.x); pk.us[1] = f2bf(s.y); pk.us[2] = f2bf(s.z); pk.us[3] = f2bf(s.w);
    *(uint2*)(Sred + (size_t)bh * 32768 + dl * 256 + cq6 * 4) = pk.u;
}

// ---------------- K4: per bh: ctx = (Sred @ Wv^T)*zinv; Wc = w_out @ ctx^T ----------
__global__ __launch_bounds__(256) void k_redwc(const unsigned short* __restrict__ Sred,
                                               const float* __restrict__ zacc,
                                               const unsigned short* __restrict__ wbf,
                                               const float* __restrict__ w_out,
                                               unsigned short* __restrict__ Wc) {
    __shared__ unsigned short Ds[128 * 136];   // ctx bf16 [d][e]
    __shared__ float zinv[128];
    const int t = threadIdx.x;
    const int bh = blockIdx.x;  const int b = bh >> 2, h = bh & 3;
    const int lane = t & 63, wv = t >> 6, quad = lane >> 4, l15 = lane & 15;

    if (t < 128) zinv[t] = 1.0f / zacc[b * 512 + h * 128 + t];
    __syncthreads();

    // GEMM-A: ctx[d][e] = sum_c Sred[d][c] * Wv_h[e][c]
    {
        const int wm = (wv & 1) * 64, wn = (wv >> 1) * 64;
        const unsigned short* Sb = Sred + (size_t)bh * 32768;
        const unsigned short* Vb = wbf + (size_t)(1024 + h * 128) * CIN;
        v4f acc[4][4];
        #pragma unroll
        for (int i = 0; i < 4; i++)
            #pragma unroll
            for (int j = 0; j < 4; j++) acc[i][j] = (v4f)0.f;
        for (int kk = 0; kk < CIN; kk += 32) {
            v8s af[4], bfr[4];
            #pragma unroll
            for (int mi = 0; mi < 4; mi++) {
                union { v8s v; uint4 u; } rr;
                rr.u = *(const uint4*)(Sb + (size_t)(wm + mi * 16 + l15) * 256 + kk + quad * 8);
                af[mi] = rr.v;
            }
            #pragma unroll
            for (int ni = 0; ni < 4; ni++) {
                union { v8s v; uint4 u; } rr;
                rr.u = *(const uint4*)(Vb + (size_t)(wn + ni * 16 + l15) * 256 + kk + quad * 8);
                bfr[ni] = rr.v;
            }
            #pragma unroll
            for (int mi = 0; mi < 4; mi++)
                #pragma unroll
                for (int ni = 0; ni < 4; ni++)
                    acc[mi][ni] = __builtin_amdgcn_mfma_f32_16x16x32_bf16(af[mi], bfr[ni], acc[mi][ni], 0, 0, 0);
        }
        float zq[4][4];
        #pragma unroll
        for (int mi = 0; mi < 4; mi++)
            #pragma unroll
            for (int rr = 0; rr < 4; rr++)
                zq[mi][rr] = zinv[wm + mi * 16 + quad * 4 + rr];
        #pragma unroll
        for (int mi = 0; mi < 4; mi++)
            #pragma unroll
            for (int ni = 0; ni < 4; ni++)
                #pragma unroll
                for (int rr = 0; rr < 4; rr++)
                    Ds[(wm + mi * 16 + quad * 4 + rr) * 136 + wn + ni * 16 + l15] =
                        f2bf(acc[mi][ni][rr] * zq[mi][rr]);
    }
    __syncthreads();

    // GEMM-B: Wc_h[o][d] = sum_e w_out[o][h*128+e] * ctx[d][e]
    {
        const int wm = wv * 64;
        v4f acc[4][8];
        #pragma unroll
        for (int i = 0; i < 4; i++)
            #pragma unroll
            for (int j = 0; j < 8; j++) acc[i][j] = (v4f)0.f;
        for (int kk = 0; kk < 128; kk += 32) {
            v8s af[4], bfr[8];
            #pragma unroll
            for (int mi = 0; mi < 4; mi++) {
                int o = wm + mi * 16 + l15;
                const float* wp = w_out + (size_t)o * HID + h * 128 + kk + quad * 8;
                float4 f0 = *(const float4*)wp;
                float4 f1 = *(const float4*)(wp + 4);
                union { v8s v; unsigned short s[8]; } r;
                r.s[0] = f2bf(f0.x); r.s[1] = f2bf(f0.y); r.s[2] = f2bf(f0.z); r.s[3] = f2bf(f0.w);
                r.s[4] = f2bf(f1.x); r.s[5] = f2bf(f1.y); r.s[6] = f2bf(f1.z); r.s[7] = f2bf(f1.w);
                af[mi] = r.v;
            }
            #pragma unroll
            for (int ni = 0; ni < 8; ni++) {
                union { v8s v; uint4 u; } r;
                r.u = *(const uint4*)(&Ds[(ni * 16 + l15) * 136 + kk + quad * 8]);
                bfr[ni] = r.v;
            }
            #pragma unroll
            for (int mi = 0; mi < 4; mi++)
                #pragma unroll
                for (int ni = 0; ni < 8; ni++)
                    acc[mi][ni] = __builtin_amdgcn_mfma_f32_16x16x32_bf16(af[mi], bfr[ni], acc[mi][ni], 0, 0, 0);
        }
        #pragma unroll
        for (int ni = 0; ni < 8; ni++) {
            int d = ni * 16 + l15;
            #pragma unroll
            for (int mi = 0; mi < 4; mi++)
                #pragma unroll
                for (int rr = 0; rr < 4; rr++) {
                    int o = wm + mi * 16 + quad * 4 + rr;
                    Wc[((size_t)b * 256 + o) * HID + h * 128 + d] = f2bf(acc[mi][ni][rr]);
                }
        }
    }
}

// ---------------- K5: Weff = Wc @ wq_q^T (C^T: M=c, N=o), BK=64 swizzled ------------
__global__ __launch_bounds__(256) void k_chain(const unsigned short* __restrict__ Wc,
                                               const unsigned short* __restrict__ wqT,
                                               unsigned short* __restrict__ Weff) {
    __shared__ __align__(16) unsigned short As[128 * 64];   // c-rows (wqT)
    __shared__ __align__(16) unsigned short Bs[128 * 64];   // o-rows (Wc)
    const int t = threadIdx.x;
    const int c0 = blockIdx.x * 128, o0 = blockIdx.y * 128, bz = blockIdx.z;
    const int lane = t & 63, wv = t >> 6, quad = lane >> 4, l15 = lane & 15;
    const int wmC = (wv & 1) * 64, wnO = (wv >> 1) * 64;

    const int srow8 = lane >> 3, sslot = lane & 7;
    const int scol = ((sslot - srow8) & 7) * 8;
    const int sw0 = ((quad + l15) & 7) * 8;

    const unsigned short* Ag = wqT + (size_t)(c0 + wv * 32 + srow8) * HID + scol;
    const unsigned short* Bg = Wc + ((size_t)bz * 256 + o0 + wv * 32 + srow8) * HID + scol;
    unsigned short* Al = As + wv * 32 * 64;
    unsigned short* Bl = Bs + wv * 32 * 64;

    v4f acc[4][4];
    #pragma unroll
    for (int i = 0; i < 4; i++)
        #pragma unroll
        for (int j = 0; j < 4; j++) acc[i][j] = (v4f)0.f;

    for (int kk = 0; kk < HID; kk += 64) {
        #pragma unroll
        for (int cc = 0; cc < 4; cc++) {
            gld_lds16(Ag + (size_t)(cc * 8) * HID + kk, Al + cc * 8 * 64);
            gld_lds16(Bg + (size_t)(cc * 8) * HID + kk, Bl + cc * 8 * 64);
        }
        __syncthreads();
        #pragma unroll
        for (int h = 0; h < 2; h++) {
            const int sw = sw0 ^ (h * 32);
            v8s af[4], bfr[4];
            #pragma unroll
            for (int mi = 0; mi < 4; mi++) {
                union { v8s v; uint4 u; } rr;
                rr.u = *(const uint4*)(&As[(wmC + mi * 16 + l15) * 64 + sw]);
                af[mi] = rr.v;
            }
            #pragma unroll
            for (int ni = 0; ni < 4; ni++) {
                union { v8s v; uint4 u; } rr;
                rr.u = *(const uint4*)(&Bs[(wnO + ni * 16 + l15) * 64 + sw]);
                bfr[ni] = rr.v;
            }
            #pragma unroll
            for (int mi = 0; mi < 4; mi++)
                #pragma unroll
                for (int ni = 0; ni < 4; ni++)
                    acc[mi][ni] = __builtin_amdgcn_mfma_f32_16x16x32_bf16(af[mi], bfr[ni], acc[mi][ni], 0, 0, 0);
        }
        __syncthreads();
    }
    #pragma unroll
    for (int ni = 0; ni < 4; ni++) {
        const int o = o0 + wnO + ni * 16 + l15;
        #pragma unroll
        for (int mi = 0; mi < 4; mi++) {
            const int c = c0 + wmC + mi * 16 + quad * 4;
            union { unsigned short s[4]; uint2 u; } p;
            #pragma unroll
            for (int rr = 0; rr < 4; rr++) p.s[rr] = f2bf(acc[mi][ni][rr]);
            *(uint2*)(Weff + ((size_t)bz * 256 + o) * 256 + c) = p.u;
        }
    }
}

// ---------------- K6: y = Weff @ x + b_out (C^T: M=n, N=o), BK=64 swizzled ----------
__global__ __launch_bounds__(256) void k_y(const unsigned short* __restrict__ Weff,
                                           const unsigned short* __restrict__ xT,
                                           const float* __restrict__ b_out,
                                           float* __restrict__ y) {
    __shared__ __align__(16) unsigned short As[128 * 64];   // n-rows (xT)
    __shared__ __align__(16) unsigned short Bs[128 * 64];   // o-rows (Weff)
    const int t = threadIdx.x;
    const int o0 = blockIdx.x * 128;
    const int n0 = blockIdx.y * 128;
    const int bz = blockIdx.z;
    const int lane = t & 63, wv = t >> 6, quad = lane >> 4, l15 = lane & 15;
    const int wmN = (wv & 1) * 64, wnO = (wv >> 1) * 64;

    const int srow8 = lane >> 3, sslot = lane & 7;
    const int scol = ((sslot - srow8) & 7) * 8;
    const int sw0 = ((quad + l15) & 7) * 8;

    const unsigned short* Ag = xT + ((size_t)bz * NSP + n0 + wv * 32 + srow8) * CIN + scol;
    const unsigned short* Bg = Weff + ((size_t)bz * 256 + o0 + wv * 32 + srow8) * CIN + scol;
    unsigned short* Al = As + wv * 32 * 64;
    unsigned short* Bl = Bs + wv * 32 * 64;

    v4f acc[4][4];
    #pragma unroll
    for (int i = 0; i < 4; i++)
        #pragma unroll
        for (int j = 0; j < 4; j++) acc[i][j] = (v4f)0.f;

    for (int kk = 0; kk < CIN; kk += 64) {
        #pragma unroll
        for (int cc = 0; cc < 4; cc++) {
            gld_lds16(Ag + (size_t)(cc * 8) * CIN + kk, Al + cc * 8 * 64);
            gld_lds16(Bg + (size_t)(cc * 8) * CIN + kk, Bl + cc * 8 * 64);
        }
        __syncthreads();
        #pragma unroll
        for (int h = 0; h < 2; h++) {
            const int sw = sw0 ^ (h * 32);
            v8s af[4], bfr[4];
            #pragma unroll
            for (int mi = 0; mi < 4; mi++) {
                union { v8s v; uint4 u; } rr;
                rr.u = *(const uint4*)(&As[(wmN + mi * 16 + l15) * 64 + sw]);
                af[mi] = rr.v;
            }
            #pragma unroll
            for (int ni = 0; ni < 4; ni++) {
                union { v8s v; uint4 u; } rr;
                rr.u = *(const uint4*)(&Bs[(wnO + ni * 16 + l15) * 64 + sw]);
                bfr[ni] = rr.v;
            }
            #pragma unroll
            for (int mi = 0; mi < 4; mi++)
                #pragma unroll
                for (int ni = 0; ni < 4; ni++)
                    acc[mi][ni] = __builtin_amdgcn_mfma_f32_16x16x32_bf16(af[mi], bfr[ni], acc[mi][ni], 0, 0, 0);
        }
        __syncthreads();
    }
    #pragma unroll
    for (int ni = 0; ni < 4; ni++) {
        const int o = o0 + wnO + ni * 16 + l15;
        const float bias = b_out[o];
        #pragma unroll
        for (int mi = 0; mi < 4; mi++) {
            const int n = n0 + wmN + mi * 16 + quad * 4;
            v4f v = acc[mi][ni];
            v[0] += bias; v[1] += bias; v[2] += bias; v[3] += bias;
            *(v4f*)(y + ((size_t)bz * 256 + o) * NSP + n) = v;
        }
    }
}

extern "C" void kernel_launch(void* const* d_in, const int* in_sizes, int n_in,
                              void* d_out, int out_size, void* d_ws, size_t ws_size,
                              hipStream_t stream) {
    (void)in_sizes; (void)n_in; (void)out_size; (void)ws_size;
    const float* x     = (const float*)d_in[0];
    const float* w_qkv = (const float*)d_in[1];
    const float* w_out = (const float*)d_in[2];
    const float* b_out = (const float*)d_in[3];
    float* y = (float*)d_out;
    char* ws = (char*)d_ws;

    unsigned short* xT   = (unsigned short*)(ws);                 //  33,554,432 B
    unsigned short* xbf  = (unsigned short*)(ws + 33554432);      //  33,554,432 B
    float*          Sp   = (float*)(ws + 67108864);               //  33,554,432 B
    float*          zacc = (float*)(ws + 100663296);              //      32,768 B
    unsigned short* Sred = (unsigned short*)(ws + 100696064);     //   4,194,304 B
    unsigned short* Wc   = (unsigned short*)(ws + 104890368);     //   4,194,304 B
    unsigned short* Weff = (unsigned short*)(ws + 109084672);     //   2,097,152 B
    unsigned short* wbf  = (unsigned short*)(ws + 111181824);     //     786,432 B
    unsigned short* wqT  = (unsigned short*)(ws + 111968256);     //     524,288 B

    k_prep <<<dim3(4352),       256, 0, stream>>>(x, w_qkv, xbf, xT, wbf, wqT, zacc);
    k_ks   <<<dim3(512),        512, 0, stream>>>(wbf, xT, xbf, Sp, zacc);
    k_sred <<<dim3(2048),       256, 0, stream>>>(Sp, Sred);
    k_redwc<<<dim3(64),         256, 0, stream>>>(Sred, zacc, wbf, w_out, Wc);
    k_chain<<<dim3(2, 2, 16),   256, 0, stream>>>(Wc, wqT, Weff);
    k_y    <<<dim3(2, 32, 16),  256, 0, stream>>>(Weff, xT, b_out, y);
}

// Round 10
// 221.948 us; speedup vs baseline: 1.0936x; 1.0936x over previous
//
#include <hip/hip_runtime.h>

#define BATCH 16
#define CIN   256
#define NSP   4096
#define HID   512

typedef short v8s __attribute__((ext_vector_type(8)));
typedef float v4f __attribute__((ext_vector_type(4)));

__device__ __forceinline__ unsigned short f2bf(float f) {
    union { float f; unsigned u; } a; a.f = f;
    unsigned r = a.u + 0x7fffu + ((a.u >> 16) & 1u);
    return (unsigned short)(r >> 16);
}

__device__ __forceinline__ void gld_lds16(const unsigned short* g, unsigned short* l) {
    __builtin_amdgcn_global_load_lds(
        (const __attribute__((address_space(1))) unsigned int*)g,
        (__attribute__((address_space(3))) unsigned int*)l,
        16, 0, 0);
}

// Swizzled [rows][64] bf16 LDS tile: slot s (8 shorts) of row r stored at slot (s+r)&7.
// Staging lane (srow8=lane>>3, sslot=lane&7) loads global col ((sslot-srow8)&7)*8.
// Reader of (row r, k-half h): LDS col = ((quad + r)&7)*8 ^ (h*32).  0 conflicts.

// ---------------- P: weights prep + x prep + zacc zero (merged) ---------------------
__global__ __launch_bounds__(256) void k_prep(const float* __restrict__ x,
                                              const float* __restrict__ wq,
                                              unsigned short* __restrict__ xbf,
                                              unsigned short* __restrict__ xT,
                                              unsigned short* __restrict__ wbf,
                                              unsigned short* __restrict__ wqT,
                                              float* __restrict__ zacc) {
    const int bid = blockIdx.x;
    const int t = threadIdx.x;
    if (bid >= 4320) {                        // 32 blocks: zero zacc (16x512 fp32)
        zacc[(bid - 4320) * 256 + t] = 0.f;
        return;
    }
    if (bid >= 4096) {
        const int wid = bid - 4096;
        if (wid < 192) {                      // bf16 convert of full w_qkv
            const int g = wid * 256 + t;
            const float4 f0 = *(const float4*)(wq + (size_t)g * 8);
            const float4 f1 = *(const float4*)(wq + (size_t)g * 8 + 4);
            union { unsigned short s[8]; uint4 u; } p;
            p.s[0] = f2bf(f0.x); p.s[1] = f2bf(f0.y); p.s[2] = f2bf(f0.z); p.s[3] = f2bf(f0.w);
            p.s[4] = f2bf(f1.x); p.s[5] = f2bf(f1.y); p.s[6] = f2bf(f1.z); p.s[7] = f2bf(f1.w);
            *(uint4*)(wbf + (size_t)g * 8) = p.u;
            return;
        }
        __shared__ float tile[64 * 65];       // 32 blocks: wqT transpose (q part)
        const int bb = wid - 192;
        const int u0 = (bb & 7) * 64, c0 = (bb >> 3) * 64;
        {
            const int cl = (t & 15) * 4, ul = t >> 4;
            #pragma unroll
            for (int i = 0; i < 4; i++) {
                int u = ul + i * 16;
                const float4 f = *(const float4*)(wq + (size_t)(u0 + u) * CIN + c0 + cl);
                *(float4*)(&tile[u * 65 + cl]) = f;
            }
        }
        __syncthreads();
        {
            const int ul4 = (t & 15) * 4, cl = t >> 4;
            #pragma unroll
            for (int i = 0; i < 4; i++) {
                int c = cl + i * 16;
                union { unsigned short s[4]; uint2 u; } p;
                #pragma unroll
                for (int j = 0; j < 4; j++)
                    p.s[j] = f2bf(tile[(ul4 + j) * 65 + c]);
                *(uint2*)(wqT + (size_t)(c0 + c) * HID + u0 + ul4) = p.u;
            }
        }
        return;
    }
    // x prep: 4096 blocks of 64x64 tiles
    __shared__ float tile[64 * 65];
    const int n0 = (bid & 63) * 64, c0 = ((bid >> 6) & 3) * 64, bz = bid >> 8;
    const float* xb = x + (size_t)bz * CIN * NSP;
    {
        const int nl = (t & 15) * 4, cl = t >> 4;
        #pragma unroll
        for (int i = 0; i < 4; i++) {
            int c = cl + i * 16;
            const float4 f = *(const float4*)(xb + (size_t)(c0 + c) * NSP + n0 + nl);
            *(float4*)(&tile[c * 65 + nl]) = f;
            union { unsigned short s[4]; uint2 u; } p;
            p.s[0] = f2bf(f.x); p.s[1] = f2bf(f.y); p.s[2] = f2bf(f.z); p.s[3] = f2bf(f.w);
            *(uint2*)(xbf + ((size_t)bz * CIN + c0 + c) * NSP + n0 + nl) = p.u;
        }
    }
    __syncthreads();
    {
        const int cl4 = (t & 15) * 4, nl = t >> 4;
        #pragma unroll
        for (int i = 0; i < 4; i++) {
            int n = nl + i * 16;
            union { unsigned short s[4]; uint2 u; } p;
            #pragma unroll
            for (int j = 0; j < 4; j++)
                p.s[j] = f2bf(tile[(cl4 + j) * 65 + n]);
            *(uint2*)(xT + ((size_t)bz * NSP + n0 + n) * CIN + c0 + cl4) = p.u;
        }
    }
}

// ---------------- KS: fused  E = exp(Wk @ x)  and  S += xbf @ E^T  ------------------
// v10 k_ks = exact R1 version (measured 47.08us, best of 8 structural variants).
// Grid 256 = 16 b x 4 dblk(128 d) x 4 nchunk. 512 thr = 8 waves, 1 blk/CU.
__global__ __launch_bounds__(512, 2) void k_ks(const unsigned short* __restrict__ wbf,
                                               const unsigned short* __restrict__ xT,
                                               const unsigned short* __restrict__ xbf,
                                               float* __restrict__ Sp,
                                               float* __restrict__ zacc) {
    __shared__ __align__(16) unsigned short A1s[2][2][128][64];  // 64 KB: [kkpair][kk][n][64]
    __shared__ __align__(16) unsigned short A2s[2][256][64];     // 64 KB: [kst][c][64]
    __shared__ __align__(16) unsigned short Es[128 * 128];       // 32 KB: [d][n], slot-rotated

    const int t = threadIdx.x;
    const int id = blockIdx.x;
    const int bz = id & 15, dblk = (id >> 4) & 3, nc = id >> 6;
    const int d0 = dblk * 128;
    const int nbase = nc * 1024;
    const int lane = t & 63, wv = t >> 6, quad = lane >> 4, l15 = lane & 15;
    const int srow8 = lane >> 3, sslot = lane & 7;
    const int scol = ((sslot - srow8) & 7) * 8;
    const int sw0 = ((quad + l15) & 7) * 8;
    // G1 wave role: E[d 128][n 128]: wn = n-half (64), wd1 = d-quarter (32)
    const int wn = wv & 1, wd1 = wv >> 1;
    // G2 wave role: S[c 256][d 128]: wc = c-quarter (64), wd2 = d-half (64)
    const int wc = wv & 3, wd2 = wv >> 2;

    auto STAGE_A1 = [&](int half, int nrow0) {
        #pragma unroll
        for (int i = 0; i < 4; i++) {
            const int flat = wv * 4 + i;          // 0..31
            const int kl = flat >> 4, rb = flat & 15;
            gld_lds16(xT + ((size_t)bz * NSP + nrow0 + rb * 8 + srow8) * CIN + (half * 2 + kl) * 64 + scol,
                      &A1s[half][kl][rb * 8][0]);
        }
    };
    auto STAGE_A2 = [&](int n0s) {
        #pragma unroll
        for (int i = 0; i < 8; i++) {
            const int flat = wv * 8 + i;          // 0..63
            const int kst = flat >> 5, rb = flat & 31;
            gld_lds16(xbf + ((size_t)bz * CIN + rb * 8 + srow8) * NSP + n0s + kst * 64 + scol,
                      &A2s[kst][rb * 8][0]);
        }
    };

    // ---- prologue: stage Wk (rows 512+d0..+128 of wbf) into A2 region, hoist frags --
    {
        #pragma unroll
        for (int i = 0; i < 8; i++) {
            const int flat = wv * 8 + i;          // 0..63
            const int kk = flat >> 4, rb = flat & 15;
            gld_lds16(wbf + (size_t)(512 + d0 + rb * 8 + srow8) * CIN + kk * 64 + scol,
                      &A2s[0][0][0] + (kk * 128 + rb * 8) * 64);
        }
    }
    __syncthreads();
    v8s Wkf[4][2][2];                             // [kk][ni (16-d)][h] = 64 VGPRs
    #pragma unroll
    for (int kk = 0; kk < 4; kk++)
        #pragma unroll
        for (int ni = 0; ni < 2; ni++)
            #pragma unroll
            for (int h = 0; h < 2; h++) {
                union { v8s v; uint4 u; } rr;
                rr.u = *(const uint4*)(&A2s[0][0][0] +
                        (size_t)(kk * 128 + wd1 * 32 + ni * 16 + l15) * 64 + (sw0 ^ (h * 32)));
                Wkf[kk][ni][h] = rr.v;
            }
    __syncthreads();

    v4f acc2[4][4];                               // S partial [c][d]
    #pragma unroll
    for (int i = 0; i < 4; i++)
        #pragma unroll
        for (int j = 0; j < 4; j++) acc2[i][j] = (v4f)0.f;
    float za[2] = {0.f, 0.f};

    STAGE_A1(0, nbase);
    STAGE_A1(1, nbase);

    for (int nt = 0; nt < 8; nt++) {
        const int n0s = nbase + nt * 128;
        __syncthreads();                          // A: A1 ready; A2, Es free (prev G2 done)
        STAGE_A2(n0s);                            // hidden under G1

        v4f acc1[4][2];
        #pragma unroll
        for (int i = 0; i < 4; i++)
            #pragma unroll
            for (int j = 0; j < 2; j++) acc1[i][j] = (v4f)0.f;

        __builtin_amdgcn_s_setprio(1);
        #pragma unroll
        for (int kk = 0; kk < 4; kk++) {
            #pragma unroll
            for (int h = 0; h < 2; h++) {
                v8s af[4];
                #pragma unroll
                for (int mi = 0; mi < 4; mi++) {
                    union { v8s v; uint4 u; } rr;
                    rr.u = *(const uint4*)(&A1s[kk >> 1][kk & 1][wn * 64 + mi * 16 + l15][0] + (sw0 ^ (h * 32)));
                    af[mi] = rr.v;
                }
                #pragma unroll
                for (int mi = 0; mi < 4; mi++)
                    #pragma unroll
                    for (int ni = 0; ni < 2; ni++)
                        acc1[mi][ni] = __builtin_amdgcn_mfma_f32_16x16x32_bf16(af[mi], Wkf[kk][ni][h], acc1[mi][ni], 0, 0, 0);
            }
        }
        __builtin_amdgcn_s_setprio(0);

        // E epilogue: exp, z accumulate, write Es (slot-rotated: slot s of row d at (s+d)&7)
        #pragma unroll
        for (int ni = 0; ni < 2; ni++) {
            const int d = wd1 * 32 + ni * 16 + l15;
            #pragma unroll
            for (int mi = 0; mi < 4; mi++) {
                union { unsigned short s[4]; uint2 u; } p;
                #pragma unroll
                for (int rr = 0; rr < 4; rr++) {
                    float e = __expf(acc1[mi][ni][rr]);
                    za[ni] += e;
                    p.s[rr] = f2bf(e);
                }
                const int slot = (mi * 2 + (quad >> 1) + d) & 7;
                *(uint2*)(&Es[d * 128 + wn * 64 + slot * 8 + (quad & 1) * 4]) = p.u;
            }
        }
        __syncthreads();                          // B: A2 + Es ready; A1 free
        if (nt < 7) {
            STAGE_A1(0, n0s + 128);               // hidden under G2
            STAGE_A1(1, n0s + 128);
        }

        __builtin_amdgcn_s_setprio(1);
        #pragma unroll
        for (int kst = 0; kst < 2; kst++) {
            #pragma unroll
            for (int h = 0; h < 2; h++) {
                v8s af[4], bfr[4];
                #pragma unroll
                for (int mi = 0; mi < 4; mi++) {
                    union { v8s v; uint4 u; } rr;
                    rr.u = *(const uint4*)(&A2s[kst][wc * 64 + mi * 16 + l15][0] + (sw0 ^ (h * 32)));
                    af[mi] = rr.v;
                }
                #pragma unroll
                for (int ni = 0; ni < 4; ni++) {
                    union { v8s v; uint4 u; } rr;
                    rr.u = *(const uint4*)(&Es[(wd2 * 64 + ni * 16 + l15) * 128 + kst * 64 + (sw0 ^ (h * 32))]);
                    bfr[ni] = rr.v;
                }
                #pragma unroll
                for (int mi = 0; mi < 4; mi++)
                    #pragma unroll
                    for (int ni = 0; ni < 4; ni++)
                        acc2[mi][ni] = __builtin_amdgcn_mfma_f32_16x16x32_bf16(af[mi], bfr[ni], acc2[mi][ni], 0, 0, 0);
            }
        }
        __builtin_amdgcn_s_setprio(0);
    }

    // z: reduce across quads, one atomic per (d) per wave
    #pragma unroll
    for (int ni = 0; ni < 2; ni++) {
        float z = za[ni];
        z += __shfl_xor(z, 16);
        z += __shfl_xor(z, 32);
        if (quad == 0)
            atomicAdd(&zacc[bz * 512 + d0 + wd1 * 32 + ni * 16 + l15], z);
    }

    // Sp store: slice ((bh*2+ch)*4 + nc), [128 d][128 c] fp32  (bh = bz*4 + dblk)
    const int ch = wc >> 1;
    float* outp = Sp + ((size_t)((bz * 4 + dblk) * 2 + ch) * 4 + nc) * 16384;
    #pragma unroll
    for (int ni = 0; ni < 4; ni++) {
        const int dl = wd2 * 64 + ni * 16 + l15;
        #pragma unroll
        for (int mi = 0; mi < 4; mi++) {
            const int cl = (wc & 1) * 64 + mi * 16 + quad * 4;
            *(v4f*)(outp + dl * 128 + cl) = acc2[mi][ni];
        }
    }
}

// ---------------- K4: per bh: reduce Sp -> LDS; ctx = (S @ Wv^T)*zinv; Wc ------------
// v10: k_sred folded in; R9's bug fixed (loop was 64 iters = 16384 quads, but a
// bh slice has 8192 quads -> LDS overflow; now 32 iters). Summation order and
// rounding identical to the old k_sred.
__global__ __launch_bounds__(256) void k_redwc(const float* __restrict__ Sp,
                                               const float* __restrict__ zacc,
                                               const unsigned short* __restrict__ wbf,
                                               const float* __restrict__ w_out,
                                               unsigned short* __restrict__ Wc) {
    __shared__ unsigned short Ss[128 * 264];   // Sred tile bf16 [d][c], padded rows
    __shared__ unsigned short Ds[128 * 136];   // ctx bf16 [d][e]
    __shared__ float zinv[128];
    const int t = threadIdx.x;
    const int bh = blockIdx.x;  const int b = bh >> 2, h = bh & 3;
    const int lane = t & 63, wv = t >> 6, quad = lane >> 4, l15 = lane & 15;

    if (t < 128) zinv[t] = 1.0f / zacc[b * 512 + h * 128 + t];

    // ---- Sp 4-slice reduce -> Ss: 8192 quads = 32 iters x 256 threads ----
    {
        const float* base = Sp + ((size_t)bh * 2) * 4 * 16384;
        #pragma unroll 4
        for (int i = 0; i < 32; i++) {
            const int q = i * 256 + t;            // 8192 quads: [dl 128][cq6 64]
            const int dl = q >> 6, cq6 = q & 63;
            const int ch = cq6 >> 5, clq = cq6 & 31;
            const float* p = base + (size_t)ch * 4 * 16384 + dl * 128 + clq * 4;
            float4 s = *(const float4*)p;
            #pragma unroll
            for (int kc = 1; kc < 4; kc++) {
                const float4 f = *(const float4*)(p + (size_t)kc * 16384);
                s.x += f.x; s.y += f.y; s.z += f.z; s.w += f.w;
            }
            union { unsigned short us[4]; uint2 u; } pk;
            pk.us[0] = f2bf(s.x); pk.us[1] = f2bf(s.y); pk.us[2] = f2bf(s.z); pk.us[3] = f2bf(s.w);
            *(uint2*)(&Ss[dl * 264 + cq6 * 4]) = pk.u;
        }
    }
    __syncthreads();

    // GEMM-A: ctx[d][e] = sum_c Ss[d][c] * Wv_h[e][c]
    {
        const int wm = (wv & 1) * 64, wn = (wv >> 1) * 64;
        const unsigned short* Vb = wbf + (size_t)(1024 + h * 128) * CIN;
        v4f acc[4][4];
        #pragma unroll
        for (int i = 0; i < 4; i++)
            #pragma unroll
            for (int j = 0; j < 4; j++) acc[i][j] = (v4f)0.f;
        for (int kk = 0; kk < CIN; kk += 32) {
            v8s af[4], bfr[4];
            #pragma unroll
            for (int mi = 0; mi < 4; mi++) {
                union { v8s v; uint4 u; } rr;
                rr.u = *(const uint4*)(&Ss[(wm + mi * 16 + l15) * 264 + kk + quad * 8]);
                af[mi] = rr.v;
            }
            #pragma unroll
            for (int ni = 0; ni < 4; ni++) {
                union { v8s v; uint4 u; } rr;
                rr.u = *(const uint4*)(Vb + (size_t)(wn + ni * 16 + l15) * 256 + kk + quad * 8);
                bfr[ni] = rr.v;
            }
            #pragma unroll
            for (int mi = 0; mi < 4; mi++)
                #pragma unroll
                for (int ni = 0; ni < 4; ni++)
                    acc[mi][ni] = __builtin_amdgcn_mfma_f32_16x16x32_bf16(af[mi], bfr[ni], acc[mi][ni], 0, 0, 0);
        }
        float zq[4][4];
        #pragma unroll
        for (int mi = 0; mi < 4; mi++)
            #pragma unroll
            for (int rr = 0; rr < 4; rr++)
                zq[mi][rr] = zinv[wm + mi * 16 + quad * 4 + rr];
        #pragma unroll
        for (int mi = 0; mi < 4; mi++)
            #pragma unroll
            for (int ni = 0; ni < 4; ni++)
                #pragma unroll
                for (int rr = 0; rr < 4; rr++)
                    Ds[(wm + mi * 16 + quad * 4 + rr) * 136 + wn + ni * 16 + l15] =
                        f2bf(acc[mi][ni][rr] * zq[mi][rr]);
    }
    __syncthreads();

    // GEMM-B: Wc_h[o][d] = sum_e w_out[o][h*128+e] * ctx[d][e]
    {
        const int wm = wv * 64;
        v4f acc[4][8];
        #pragma unroll
        for (int i = 0; i < 4; i++)
            #pragma unroll
            for (int j = 0; j < 8; j++) acc[i][j] = (v4f)0.f;
        for (int kk = 0; kk < 128; kk += 32) {
            v8s af[4], bfr[8];
            #pragma unroll
            for (int mi = 0; mi < 4; mi++) {
                int o = wm + mi * 16 + l15;
                const float* wp = w_out + (size_t)o * HID + h * 128 + kk + quad * 8;
                float4 f0 = *(const float4*)wp;
                float4 f1 = *(const float4*)(wp + 4);
                union { v8s v; unsigned short s[8]; } r;
                r.s[0] = f2bf(f0.x); r.s[1] = f2bf(f0.y); r.s[2] = f2bf(f0.z); r.s[3] = f2bf(f0.w);
                r.s[4] = f2bf(f1.x); r.s[5] = f2bf(f1.y); r.s[6] = f2bf(f1.z); r.s[7] = f2bf(f1.w);
                af[mi] = r.v;
            }
            #pragma unroll
            for (int ni = 0; ni < 8; ni++) {
                union { v8s v; uint4 u; } r;
                r.u = *(const uint4*)(&Ds[(ni * 16 + l15) * 136 + kk + quad * 8]);
                bfr[ni] = r.v;
            }
            #pragma unroll
            for (int mi = 0; mi < 4; mi++)
                #pragma unroll
                for (int ni = 0; ni < 8; ni++)
                    acc[mi][ni] = __builtin_amdgcn_mfma_f32_16x16x32_bf16(af[mi], bfr[ni], acc[mi][ni], 0, 0, 0);
        }
        #pragma unroll
        for (int ni = 0; ni < 8; ni++) {
            int d = ni * 16 + l15;
            #pragma unroll
            for (int mi = 0; mi < 4; mi++)
                #pragma unroll
                for (int rr = 0; rr < 4; rr++) {
                    int o = wm + mi * 16 + quad * 4 + rr;
                    Wc[((size_t)b * 256 + o) * HID + h * 128 + d] = f2bf(acc[mi][ni][rr]);
                }
        }
    }
}

// ---------------- K5: Weff = Wc @ wq_q^T (C^T: M=c, N=o), BK=64 swizzled ------------
__global__ __launch_bounds__(256) void k_chain(const unsigned short* __restrict__ Wc,
                                               const unsigned short* __restrict__ wqT,
                                               unsigned short* __restrict__ Weff) {
    __shared__ __align__(16) unsigned short As[128 * 64];   // c-rows (wqT)
    __shared__ __align__(16) unsigned short Bs[128 * 64];   // o-rows (Wc)
    const int t = threadIdx.x;
    const int c0 = blockIdx.x * 128, o0 = blockIdx.y * 128, bz = blockIdx.z;
    const int lane = t & 63, wv = t >> 6, quad = lane >> 4, l15 = lane & 15;
    const int wmC = (wv & 1) * 64, wnO = (wv >> 1) * 64;

    const int srow8 = lane >> 3, sslot = lane & 7;
    const int scol = ((sslot - srow8) & 7) * 8;
    const int sw0 = ((quad + l15) & 7) * 8;

    const unsigned short* Ag = wqT + (size_t)(c0 + wv * 32 + srow8) * HID + scol;
    const unsigned short* Bg = Wc + ((size_t)bz * 256 + o0 + wv * 32 + srow8) * HID + scol;
    unsigned short* Al = As + wv * 32 * 64;
    unsigned short* Bl = Bs + wv * 32 * 64;

    v4f acc[4][4];
    #pragma unroll
    for (int i = 0; i < 4; i++)
        #pragma unroll
        for (int j = 0; j < 4; j++) acc[i][j] = (v4f)0.f;

    for (int kk = 0; kk < HID; kk += 64) {
        #pragma unroll
        for (int cc = 0; cc < 4; cc++) {
            gld_lds16(Ag + (size_t)(cc * 8) * HID + kk, Al + cc * 8 * 64);
            gld_lds16(Bg + (size_t)(cc * 8) * HID + kk, Bl + cc * 8 * 64);
        }
        __syncthreads();
        #pragma unroll
        for (int h = 0; h < 2; h++) {
            const int sw = sw0 ^ (h * 32);
            v8s af[4], bfr[4];
            #pragma unroll
            for (int mi = 0; mi < 4; mi++) {
                union { v8s v; uint4 u; } rr;
                rr.u = *(const uint4*)(&As[(wmC + mi * 16 + l15) * 64 + sw]);
                af[mi] = rr.v;
            }
            #pragma unroll
            for (int ni = 0; ni < 4; ni++) {
                union { v8s v; uint4 u; } rr;
                rr.u = *(const uint4*)(&Bs[(wnO + ni * 16 + l15) * 64 + sw]);
                bfr[ni] = rr.v;
            }
            #pragma unroll
            for (int mi = 0; mi < 4; mi++)
                #pragma unroll
                for (int ni = 0; ni < 4; ni++)
                    acc[mi][ni] = __builtin_amdgcn_mfma_f32_16x16x32_bf16(af[mi], bfr[ni], acc[mi][ni], 0, 0, 0);
        }
        __syncthreads();
    }
    #pragma unroll
    for (int ni = 0; ni < 4; ni++) {
        const int o = o0 + wnO + ni * 16 + l15;
        #pragma unroll
        for (int mi = 0; mi < 4; mi++) {
            const int c = c0 + wmC + mi * 16 + quad * 4;
            union { unsigned short s[4]; uint2 u; } p;
            #pragma unroll
            for (int rr = 0; rr < 4; rr++) p.s[rr] = f2bf(acc[mi][ni][rr]);
            *(uint2*)(Weff + ((size_t)bz * 256 + o) * 256 + c) = p.u;
        }
    }
}

// ---------------- K6: y = Weff @ x + b_out (C^T: M=n, N=o), BK=64 swizzled ----------
__global__ __launch_bounds__(256) void k_y(const unsigned short* __restrict__ Weff,
                                           const unsigned short* __restrict__ xT,
                                           const float* __restrict__ b_out,
                                           float* __restrict__ y) {
    __shared__ __align__(16) unsigned short As[128 * 64];   // n-rows (xT)
    __shared__ __align__(16) unsigned short Bs[128 * 64];   // o-rows (Weff)
    const int t = threadIdx.x;
    const int o0 = blockIdx.x * 128;
    const int n0 = blockIdx.y * 128;
    const int bz = blockIdx.z;
    const int lane = t & 63, wv = t >> 6, quad = lane >> 4, l15 = lane & 15;
    const int wmN = (wv & 1) * 64, wnO = (wv >> 1) * 64;

    const int srow8 = lane >> 3, sslot = lane & 7;
    const int scol = ((sslot - srow8) & 7) * 8;
    const int sw0 = ((quad + l15) & 7) * 8;

    const unsigned short* Ag = xT + ((size_t)bz * NSP + n0 + wv * 32 + srow8) * CIN + scol;
    const unsigned short* Bg = Weff + ((size_t)bz * 256 + o0 + wv * 32 + srow8) * CIN + scol;
    unsigned short* Al = As + wv * 32 * 64;
    unsigned short* Bl = Bs + wv * 32 * 64;

    v4f acc[4][4];
    #pragma unroll
    for (int i = 0; i < 4; i++)
        #pragma unroll
        for (int j = 0; j < 4; j++) acc[i][j] = (v4f)0.f;

    for (int kk = 0; kk < CIN; kk += 64) {
        #pragma unroll
        for (int cc = 0; cc < 4; cc++) {
            gld_lds16(Ag + (size_t)(cc * 8) * CIN + kk, Al + cc * 8 * 64);
            gld_lds16(Bg + (size_t)(cc * 8) * CIN + kk, Bl + cc * 8 * 64);
        }
        __syncthreads();
        #pragma unroll
        for (int h = 0; h < 2; h++) {
            const int sw = sw0 ^ (h * 32);
            v8s af[4], bfr[4];
            #pragma unroll
            for (int mi = 0; mi < 4; mi++) {
                union { v8s v; uint4 u; } rr;
                rr.u = *(const uint4*)(&As[(wmN + mi * 16 + l15) * 64 + sw]);
                af[mi] = rr.v;
            }
            #pragma unroll
            for (int ni = 0; ni < 4; ni++) {
                union { v8s v; uint4 u; } rr;
                rr.u = *(const uint4*)(&Bs[(wnO + ni * 16 + l15) * 64 + sw]);
                bfr[ni] = rr.v;
            }
            #pragma unroll
            for (int mi = 0; mi < 4; mi++)
                #pragma unroll
                for (int ni = 0; ni < 4; ni++)
                    acc[mi][ni] = __builtin_amdgcn_mfma_f32_16x16x32_bf16(af[mi], bfr[ni], acc[mi][ni], 0, 0, 0);
        }
        __syncthreads();
    }
    #pragma unroll
    for (int ni = 0; ni < 4; ni++) {
        const int o = o0 + wnO + ni * 16 + l15;
        const float bias = b_out[o];
        #pragma unroll
        for (int mi = 0; mi < 4; mi++) {
            const int n = n0 + wmN + mi * 16 + quad * 4;
            v4f v = acc[mi][ni];
            v[0] += bias; v[1] += bias; v[2] += bias; v[3] += bias;
            *(v4f*)(y + ((size_t)bz * 256 + o) * NSP + n) = v;
        }
    }
}

extern "C" void kernel_launch(void* const* d_in, const int* in_sizes, int n_in,
                              void* d_out, int out_size, void* d_ws, size_t ws_size,
                              hipStream_t stream) {
    (void)in_sizes; (void)n_in; (void)out_size; (void)ws_size;
    const float* x     = (const float*)d_in[0];
    const float* w_qkv = (const float*)d_in[1];
    const float* w_out = (const float*)d_in[2];
    const float* b_out = (const float*)d_in[3];
    float* y = (float*)d_out;
    char* ws = (char*)d_ws;

    unsigned short* xT   = (unsigned short*)(ws);                 //  33,554,432 B
    unsigned short* xbf  = (unsigned short*)(ws + 33554432);      //  33,554,432 B
    float*          Sp   = (float*)(ws + 67108864);               //  33,554,432 B
    float*          zacc = (float*)(ws + 100663296);              //      32,768 B
    unsigned short* Wc   = (unsigned short*)(ws + 100696064);     //   4,194,304 B
    unsigned short* Weff = (unsigned short*)(ws + 104890368);     //   2,097,152 B
    unsigned short* wbf  = (unsigned short*)(ws + 106987520);     //     786,432 B
    unsigned short* wqT  = (unsigned short*)(ws + 107773952);     //     524,288 B

    k_prep <<<dim3(4352),       256, 0, stream>>>(x, w_qkv, xbf, xT, wbf, wqT, zacc);
    k_ks   <<<dim3(256),        512, 0, stream>>>(wbf, xT, xbf, Sp, zacc);
    k_redwc<<<dim3(64),         256, 0, stream>>>(Sp, zacc, wbf, w_out, Wc);
    k_chain<<<dim3(2, 2, 16),   256, 0, stream>>>(Wc, wqT, Weff);
    k_y    <<<dim3(2, 32, 16),  256, 0, stream>>>(Weff, xT, b_out, y);
}

// Round 11
// 218.127 us; speedup vs baseline: 1.1128x; 1.0175x over previous
//
#include <hip/hip_runtime.h>

#define BATCH 16
#define CIN   256
#define NSP   4096
#define HID   512

typedef short v8s __attribute__((ext_vector_type(8)));
typedef float v4f __attribute__((ext_vector_type(4)));

__device__ __forceinline__ unsigned short f2bf(float f) {
    union { float f; unsigned u; } a; a.f = f;
    unsigned r = a.u + 0x7fffu + ((a.u >> 16) & 1u);
    return (unsigned short)(r >> 16);
}

__device__ __forceinline__ float bf2f(unsigned short s) {
    union { unsigned u; float f; } a; a.u = ((unsigned)s) << 16;
    return a.f;
}

__device__ __forceinline__ void gld_lds16(const unsigned short* g, unsigned short* l) {
    __builtin_amdgcn_global_load_lds(
        (const __attribute__((address_space(1))) unsigned int*)g,
        (__attribute__((address_space(3))) unsigned int*)l,
        16, 0, 0);
}

// Swizzled [rows][64] bf16 LDS tile: slot s (8 shorts) of row r stored at slot (s+r)&7.
// Staging lane (srow8=lane>>3, sslot=lane&7) loads global col ((sslot-srow8)&7)*8.
// Reader of (row r, k-half h): LDS col = ((quad + r)&7)*8 ^ (h*32).  0 conflicts.

// ---------------- P: weights prep + x prep + zacc zero (merged) ---------------------
__global__ __launch_bounds__(256) void k_prep(const float* __restrict__ x,
                                              const float* __restrict__ wq,
                                              unsigned short* __restrict__ xbf,
                                              unsigned short* __restrict__ xT,
                                              unsigned short* __restrict__ wbf,
                                              unsigned short* __restrict__ wqT,
                                              float* __restrict__ zacc) {
    const int bid = blockIdx.x;
    const int t = threadIdx.x;
    if (bid >= 4320) {                        // 32 blocks: zero zacc (16x512 fp32)
        zacc[(bid - 4320) * 256 + t] = 0.f;
        return;
    }
    if (bid >= 4096) {
        const int wid = bid - 4096;
        if (wid < 192) {                      // bf16 convert of full w_qkv
            const int g = wid * 256 + t;
            const float4 f0 = *(const float4*)(wq + (size_t)g * 8);
            const float4 f1 = *(const float4*)(wq + (size_t)g * 8 + 4);
            union { unsigned short s[8]; uint4 u; } p;
            p.s[0] = f2bf(f0.x); p.s[1] = f2bf(f0.y); p.s[2] = f2bf(f0.z); p.s[3] = f2bf(f0.w);
            p.s[4] = f2bf(f1.x); p.s[5] = f2bf(f1.y); p.s[6] = f2bf(f1.z); p.s[7] = f2bf(f1.w);
            *(uint4*)(wbf + (size_t)g * 8) = p.u;
            return;
        }
        __shared__ float tile[64 * 65];       // 32 blocks: wqT transpose (q part)
        const int bb = wid - 192;
        const int u0 = (bb & 7) * 64, c0 = (bb >> 3) * 64;
        {
            const int cl = (t & 15) * 4, ul = t >> 4;
            #pragma unroll
            for (int i = 0; i < 4; i++) {
                int u = ul + i * 16;
                const float4 f = *(const float4*)(wq + (size_t)(u0 + u) * CIN + c0 + cl);
                *(float4*)(&tile[u * 65 + cl]) = f;
            }
        }
        __syncthreads();
        {
            const int ul4 = (t & 15) * 4, cl = t >> 4;
            #pragma unroll
            for (int i = 0; i < 4; i++) {
                int c = cl + i * 16;
                union { unsigned short s[4]; uint2 u; } p;
                #pragma unroll
                for (int j = 0; j < 4; j++)
                    p.s[j] = f2bf(tile[(ul4 + j) * 65 + c]);
                *(uint2*)(wqT + (size_t)(c0 + c) * HID + u0 + ul4) = p.u;
            }
        }
        return;
    }
    // x prep: 4096 blocks of 64x64 tiles
    __shared__ float tile[64 * 65];
    const int n0 = (bid & 63) * 64, c0 = ((bid >> 6) & 3) * 64, bz = bid >> 8;
    const float* xb = x + (size_t)bz * CIN * NSP;
    {
        const int nl = (t & 15) * 4, cl = t >> 4;
        #pragma unroll
        for (int i = 0; i < 4; i++) {
            int c = cl + i * 16;
            const float4 f = *(const float4*)(xb + (size_t)(c0 + c) * NSP + n0 + nl);
            *(float4*)(&tile[c * 65 + nl]) = f;
            union { unsigned short s[4]; uint2 u; } p;
            p.s[0] = f2bf(f.x); p.s[1] = f2bf(f.y); p.s[2] = f2bf(f.z); p.s[3] = f2bf(f.w);
            *(uint2*)(xbf + ((size_t)bz * CIN + c0 + c) * NSP + n0 + nl) = p.u;
        }
    }
    __syncthreads();
    {
        const int cl4 = (t & 15) * 4, nl = t >> 4;
        #pragma unroll
        for (int i = 0; i < 4; i++) {
            int n = nl + i * 16;
            union { unsigned short s[4]; uint2 u; } p;
            #pragma unroll
            for (int j = 0; j < 4; j++)
                p.s[j] = f2bf(tile[(cl4 + j) * 65 + n]);
            *(uint2*)(xT + ((size_t)bz * NSP + n0 + n) * CIN + c0 + cl4) = p.u;
        }
    }
}

// ---------------- KS: fused  E = exp(Wk @ x)  and  S += xbf @ E^T  ------------------
// v11 k_ks = R1 structure (47us floor across 10 variants; LDS-BW-bound per cycle
// model). Change vs R10: Sp partials stored bf16 (halves the 33.5MB Sp roundtrip;
// downstream S is bf16-rounded anyway -> ~sqrt(2)x S quantization, 3.7x headroom).
// Grid 256 = 16 b x 4 dblk(128 d) x 4 nchunk. 512 thr = 8 waves, 1 blk/CU.
__global__ __launch_bounds__(512, 2) void k_ks(const unsigned short* __restrict__ wbf,
                                               const unsigned short* __restrict__ xT,
                                               const unsigned short* __restrict__ xbf,
                                               unsigned short* __restrict__ Spb,
                                               float* __restrict__ zacc) {
    __shared__ __align__(16) unsigned short A1s[2][2][128][64];  // 64 KB: [kkpair][kk][n][64]
    __shared__ __align__(16) unsigned short A2s[2][256][64];     // 64 KB: [kst][c][64]
    __shared__ __align__(16) unsigned short Es[128 * 128];       // 32 KB: [d][n], slot-rotated

    const int t = threadIdx.x;
    const int id = blockIdx.x;
    const int bz = id & 15, dblk = (id >> 4) & 3, nc = id >> 6;
    const int d0 = dblk * 128;
    const int nbase = nc * 1024;
    const int lane = t & 63, wv = t >> 6, quad = lane >> 4, l15 = lane & 15;
    const int srow8 = lane >> 3, sslot = lane & 7;
    const int scol = ((sslot - srow8) & 7) * 8;
    const int sw0 = ((quad + l15) & 7) * 8;
    // G1 wave role: E[d 128][n 128]: wn = n-half (64), wd1 = d-quarter (32)
    const int wn = wv & 1, wd1 = wv >> 1;
    // G2 wave role: S[c 256][d 128]: wc = c-quarter (64), wd2 = d-half (64)
    const int wc = wv & 3, wd2 = wv >> 2;

    auto STAGE_A1 = [&](int half, int nrow0) {
        #pragma unroll
        for (int i = 0; i < 4; i++) {
            const int flat = wv * 4 + i;          // 0..31
            const int kl = flat >> 4, rb = flat & 15;
            gld_lds16(xT + ((size_t)bz * NSP + nrow0 + rb * 8 + srow8) * CIN + (half * 2 + kl) * 64 + scol,
                      &A1s[half][kl][rb * 8][0]);
        }
    };
    auto STAGE_A2 = [&](int n0s) {
        #pragma unroll
        for (int i = 0; i < 8; i++) {
            const int flat = wv * 8 + i;          // 0..63
            const int kst = flat >> 5, rb = flat & 31;
            gld_lds16(xbf + ((size_t)bz * CIN + rb * 8 + srow8) * NSP + n0s + kst * 64 + scol,
                      &A2s[kst][rb * 8][0]);
        }
    };

    // ---- prologue: stage Wk (rows 512+d0..+128 of wbf) into A2 region, hoist frags --
    {
        #pragma unroll
        for (int i = 0; i < 8; i++) {
            const int flat = wv * 8 + i;          // 0..63
            const int kk = flat >> 4, rb = flat & 15;
            gld_lds16(wbf + (size_t)(512 + d0 + rb * 8 + srow8) * CIN + kk * 64 + scol,
                      &A2s[0][0][0] + (kk * 128 + rb * 8) * 64);
        }
    }
    __syncthreads();
    v8s Wkf[4][2][2];                             // [kk][ni (16-d)][h] = 64 VGPRs
    #pragma unroll
    for (int kk = 0; kk < 4; kk++)
        #pragma unroll
        for (int ni = 0; ni < 2; ni++)
            #pragma unroll
            for (int h = 0; h < 2; h++) {
                union { v8s v; uint4 u; } rr;
                rr.u = *(const uint4*)(&A2s[0][0][0] +
                        (size_t)(kk * 128 + wd1 * 32 + ni * 16 + l15) * 64 + (sw0 ^ (h * 32)));
                Wkf[kk][ni][h] = rr.v;
            }
    __syncthreads();

    v4f acc2[4][4];                               // S partial [c][d]
    #pragma unroll
    for (int i = 0; i < 4; i++)
        #pragma unroll
        for (int j = 0; j < 4; j++) acc2[i][j] = (v4f)0.f;
    float za[2] = {0.f, 0.f};

    STAGE_A1(0, nbase);
    STAGE_A1(1, nbase);

    for (int nt = 0; nt < 8; nt++) {
        const int n0s = nbase + nt * 128;
        __syncthreads();                          // A: A1 ready; A2, Es free (prev G2 done)
        STAGE_A2(n0s);                            // hidden under G1

        v4f acc1[4][2];
        #pragma unroll
        for (int i = 0; i < 4; i++)
            #pragma unroll
            for (int j = 0; j < 2; j++) acc1[i][j] = (v4f)0.f;

        __builtin_amdgcn_s_setprio(1);
        #pragma unroll
        for (int kk = 0; kk < 4; kk++) {
            #pragma unroll
            for (int h = 0; h < 2; h++) {
                v8s af[4];
                #pragma unroll
                for (int mi = 0; mi < 4; mi++) {
                    union { v8s v; uint4 u; } rr;
                    rr.u = *(const uint4*)(&A1s[kk >> 1][kk & 1][wn * 64 + mi * 16 + l15][0] + (sw0 ^ (h * 32)));
                    af[mi] = rr.v;
                }
                #pragma unroll
                for (int mi = 0; mi < 4; mi++)
                    #pragma unroll
                    for (int ni = 0; ni < 2; ni++)
                        acc1[mi][ni] = __builtin_amdgcn_mfma_f32_16x16x32_bf16(af[mi], Wkf[kk][ni][h], acc1[mi][ni], 0, 0, 0);
            }
        }
        __builtin_amdgcn_s_setprio(0);

        // E epilogue: exp, z accumulate, write Es (slot-rotated: slot s of row d at (s+d)&7)
        #pragma unroll
        for (int ni = 0; ni < 2; ni++) {
            const int d = wd1 * 32 + ni * 16 + l15;
            #pragma unroll
            for (int mi = 0; mi < 4; mi++) {
                union { unsigned short s[4]; uint2 u; } p;
                #pragma unroll
                for (int rr = 0; rr < 4; rr++) {
                    float e = __expf(acc1[mi][ni][rr]);
                    za[ni] += e;
                    p.s[rr] = f2bf(e);
                }
                const int slot = (mi * 2 + (quad >> 1) + d) & 7;
                *(uint2*)(&Es[d * 128 + wn * 64 + slot * 8 + (quad & 1) * 4]) = p.u;
            }
        }
        __syncthreads();                          // B: A2 + Es ready; A1 free
        if (nt < 7) {
            STAGE_A1(0, n0s + 128);               // hidden under G2
            STAGE_A1(1, n0s + 128);
        }

        __builtin_amdgcn_s_setprio(1);
        #pragma unroll
        for (int kst = 0; kst < 2; kst++) {
            #pragma unroll
            for (int h = 0; h < 2; h++) {
                v8s af[4], bfr[4];
                #pragma unroll
                for (int mi = 0; mi < 4; mi++) {
                    union { v8s v; uint4 u; } rr;
                    rr.u = *(const uint4*)(&A2s[kst][wc * 64 + mi * 16 + l15][0] + (sw0 ^ (h * 32)));
                    af[mi] = rr.v;
                }
                #pragma unroll
                for (int ni = 0; ni < 4; ni++) {
                    union { v8s v; uint4 u; } rr;
                    rr.u = *(const uint4*)(&Es[(wd2 * 64 + ni * 16 + l15) * 128 + kst * 64 + (sw0 ^ (h * 32))]);
                    bfr[ni] = rr.v;
                }
                #pragma unroll
                for (int mi = 0; mi < 4; mi++)
                    #pragma unroll
                    for (int ni = 0; ni < 4; ni++)
                        acc2[mi][ni] = __builtin_amdgcn_mfma_f32_16x16x32_bf16(af[mi], bfr[ni], acc2[mi][ni], 0, 0, 0);
            }
        }
        __builtin_amdgcn_s_setprio(0);
    }

    // z: reduce across quads, one atomic per (d) per wave
    #pragma unroll
    for (int ni = 0; ni < 2; ni++) {
        float z = za[ni];
        z += __shfl_xor(z, 16);
        z += __shfl_xor(z, 32);
        if (quad == 0)
            atomicAdd(&zacc[bz * 512 + d0 + wd1 * 32 + ni * 16 + l15], z);
    }

    // Sp store (bf16): slice ((bh*2+ch)*4 + nc), [128 d][128 c]  (bh = bz*4 + dblk)
    const int ch = wc >> 1;
    unsigned short* outp = Spb + ((size_t)((bz * 4 + dblk) * 2 + ch) * 4 + nc) * 16384;
    #pragma unroll
    for (int ni = 0; ni < 4; ni++) {
        const int dl = wd2 * 64 + ni * 16 + l15;
        #pragma unroll
        for (int mi = 0; mi < 4; mi++) {
            const int cl = (wc & 1) * 64 + mi * 16 + quad * 4;
            union { unsigned short s[4]; uint2 u; } p;
            #pragma unroll
            for (int rr = 0; rr < 4; rr++) p.s[rr] = f2bf(acc2[mi][ni][rr]);
            *(uint2*)(outp + dl * 128 + cl) = p.u;
        }
    }
}

// ---------------- K4: per bh: reduce Sp(bf16) -> LDS; ctx = (S @ Wv^T)*zinv; Wc -----
// v11: reduce reads bf16 partials (half the traffic), sums in fp32, rounds once.
__global__ __launch_bounds__(256) void k_redwc(const unsigned short* __restrict__ Spb,
                                               const float* __restrict__ zacc,
                                               const unsigned short* __restrict__ wbf,
                                               const float* __restrict__ w_out,
                                               unsigned short* __restrict__ Wc) {
    __shared__ unsigned short Ss[128 * 264];   // Sred tile bf16 [d][c], padded rows
    __shared__ unsigned short Ds[128 * 136];   // ctx bf16 [d][e]
    __shared__ float zinv[128];
    const int t = threadIdx.x;
    const int bh = blockIdx.x;  const int b = bh >> 2, h = bh & 3;
    const int lane = t & 63, wv = t >> 6, quad = lane >> 4, l15 = lane & 15;

    if (t < 128) zinv[t] = 1.0f / zacc[b * 512 + h * 128 + t];

    // ---- Sp 4-slice reduce -> Ss: 8192 quads = 32 iters x 256 threads ----
    {
        const unsigned short* base = Spb + ((size_t)bh * 2) * 4 * 16384;
        #pragma unroll 4
        for (int i = 0; i < 32; i++) {
            const int q = i * 256 + t;            // 8192 quads: [dl 128][cq6 64]
            const int dl = q >> 6, cq6 = q & 63;
            const int ch = cq6 >> 5, clq = cq6 & 31;
            const unsigned short* p = base + (size_t)ch * 4 * 16384 + dl * 128 + clq * 4;
            float s0 = 0.f, s1 = 0.f, s2 = 0.f, s3 = 0.f;
            #pragma unroll
            for (int kc = 0; kc < 4; kc++) {
                union { unsigned short us[4]; uint2 u; } v;
                v.u = *(const uint2*)(p + (size_t)kc * 16384);
                s0 += bf2f(v.us[0]); s1 += bf2f(v.us[1]);
                s2 += bf2f(v.us[2]); s3 += bf2f(v.us[3]);
            }
            union { unsigned short us[4]; uint2 u; } pk;
            pk.us[0] = f2bf(s0); pk.us[1] = f2bf(s1); pk.us[2] = f2bf(s2); pk.us[3] = f2bf(s3);
            *(uint2*)(&Ss[dl * 264 + cq6 * 4]) = pk.u;
        }
    }
    __syncthreads();

    // GEMM-A: ctx[d][e] = sum_c Ss[d][c] * Wv_h[e][c]
    {
        const int wm = (wv & 1) * 64, wn = (wv >> 1) * 64;
        const unsigned short* Vb = wbf + (size_t)(1024 + h * 128) * CIN;
        v4f acc[4][4];
        #pragma unroll
        for (int i = 0; i < 4; i++)
            #pragma unroll
            for (int j = 0; j < 4; j++) acc[i][j] = (v4f)0.f;
        for (int kk = 0; kk < CIN; kk += 32) {
            v8s af[4], bfr[4];
            #pragma unroll
            for (int mi = 0; mi < 4; mi++) {
                union { v8s v; uint4 u; } rr;
                rr.u = *(const uint4*)(&Ss[(wm + mi * 16 + l15) * 264 + kk + quad * 8]);
                af[mi] = rr.v;
            }
            #pragma unroll
            for (int ni = 0; ni < 4; ni++) {
                union { v8s v; uint4 u; } rr;
                rr.u = *(const uint4*)(Vb + (size_t)(wn + ni * 16 + l15) * 256 + kk + quad * 8);
                bfr[ni] = rr.v;
            }
            #pragma unroll
            for (int mi = 0; mi < 4; mi++)
                #pragma unroll
                for (int ni = 0; ni < 4; ni++)
                    acc[mi][ni] = __builtin_amdgcn_mfma_f32_16x16x32_bf16(af[mi], bfr[ni], acc[mi][ni], 0, 0, 0);
        }
        float zq[4][4];
        #pragma unroll
        for (int mi = 0; mi < 4; mi++)
            #pragma unroll
            for (int rr = 0; rr < 4; rr++)
                zq[mi][rr] = zinv[wm + mi * 16 + quad * 4 + rr];
        #pragma unroll
        for (int mi = 0; mi < 4; mi++)
            #pragma unroll
            for (int ni = 0; ni < 4; ni++)
                #pragma unroll
                for (int rr = 0; rr < 4; rr++)
                    Ds[(wm + mi * 16 + quad * 4 + rr) * 136 + wn + ni * 16 + l15] =
                        f2bf(acc[mi][ni][rr] * zq[mi][rr]);
    }
    __syncthreads();

    // GEMM-B: Wc_h[o][d] = sum_e w_out[o][h*128+e] * ctx[d][e]
    {
        const int wm = wv * 64;
        v4f acc[4][8];
        #pragma unroll
        for (int i = 0; i < 4; i++)
            #pragma unroll
            for (int j = 0; j < 8; j++) acc[i][j] = (v4f)0.f;
        for (int kk = 0; kk < 128; kk += 32) {
            v8s af[4], bfr[8];
            #pragma unroll
            for (int mi = 0; mi < 4; mi++) {
                int o = wm + mi * 16 + l15;
                const float* wp = w_out + (size_t)o * HID + h * 128 + kk + quad * 8;
                float4 f0 = *(const float4*)wp;
                float4 f1 = *(const float4*)(wp + 4);
                union { v8s v; unsigned short s[8]; } r;
                r.s[0] = f2bf(f0.x); r.s[1] = f2bf(f0.y); r.s[2] = f2bf(f0.z); r.s[3] = f2bf(f0.w);
                r.s[4] = f2bf(f1.x); r.s[5] = f2bf(f1.y); r.s[6] = f2bf(f1.z); r.s[7] = f2bf(f1.w);
                af[mi] = r.v;
            }
            #pragma unroll
            for (int ni = 0; ni < 8; ni++) {
                union { v8s v; uint4 u; } r;
                r.u = *(const uint4*)(&Ds[(ni * 16 + l15) * 136 + kk + quad * 8]);
                bfr[ni] = r.v;
            }
            #pragma unroll
            for (int mi = 0; mi < 4; mi++)
                #pragma unroll
                for (int ni = 0; ni < 8; ni++)
                    acc[mi][ni] = __builtin_amdgcn_mfma_f32_16x16x32_bf16(af[mi], bfr[ni], acc[mi][ni], 0, 0, 0);
        }
        #pragma unroll
        for (int ni = 0; ni < 8; ni++) {
            int d = ni * 16 + l15;
            #pragma unroll
            for (int mi = 0; mi < 4; mi++)
                #pragma unroll
                for (int rr = 0; rr < 4; rr++) {
                    int o = wm + mi * 16 + quad * 4 + rr;
                    Wc[((size_t)b * 256 + o) * HID + h * 128 + d] = f2bf(acc[mi][ni][rr]);
                }
        }
    }
}

// ---------------- K5: Weff = Wc @ wq_q^T (C^T: M=c, N=o), BK=64 swizzled ------------
__global__ __launch_bounds__(256) void k_chain(const unsigned short* __restrict__ Wc,
                                               const unsigned short* __restrict__ wqT,
                                               unsigned short* __restrict__ Weff) {
    __shared__ __align__(16) unsigned short As[128 * 64];   // c-rows (wqT)
    __shared__ __align__(16) unsigned short Bs[128 * 64];   // o-rows (Wc)
    const int t = threadIdx.x;
    const int c0 = blockIdx.x * 128, o0 = blockIdx.y * 128, bz = blockIdx.z;
    const int lane = t & 63, wv = t >> 6, quad = lane >> 4, l15 = lane & 15;
    const int wmC = (wv & 1) * 64, wnO = (wv >> 1) * 64;

    const int srow8 = lane >> 3, sslot = lane & 7;
    const int scol = ((sslot - srow8) & 7) * 8;
    const int sw0 = ((quad + l15) & 7) * 8;

    const unsigned short* Ag = wqT + (size_t)(c0 + wv * 32 + srow8) * HID + scol;
    const unsigned short* Bg = Wc + ((size_t)bz * 256 + o0 + wv * 32 + srow8) * HID + scol;
    unsigned short* Al = As + wv * 32 * 64;
    unsigned short* Bl = Bs + wv * 32 * 64;

    v4f acc[4][4];
    #pragma unroll
    for (int i = 0; i < 4; i++)
        #pragma unroll
        for (int j = 0; j < 4; j++) acc[i][j] = (v4f)0.f;

    for (int kk = 0; kk < HID; kk += 64) {
        #pragma unroll
        for (int cc = 0; cc < 4; cc++) {
            gld_lds16(Ag + (size_t)(cc * 8) * HID + kk, Al + cc * 8 * 64);
            gld_lds16(Bg + (size_t)(cc * 8) * HID + kk, Bl + cc * 8 * 64);
        }
        __syncthreads();
        #pragma unroll
        for (int h = 0; h < 2; h++) {
            const int sw = sw0 ^ (h * 32);
            v8s af[4], bfr[4];
            #pragma unroll
            for (int mi = 0; mi < 4; mi++) {
                union { v8s v; uint4 u; } rr;
                rr.u = *(const uint4*)(&As[(wmC + mi * 16 + l15) * 64 + sw]);
                af[mi] = rr.v;
            }
            #pragma unroll
            for (int ni = 0; ni < 4; ni++) {
                union { v8s v; uint4 u; } rr;
                rr.u = *(const uint4*)(&Bs[(wnO + ni * 16 + l15) * 64 + sw]);
                bfr[ni] = rr.v;
            }
            #pragma unroll
            for (int mi = 0; mi < 4; mi++)
                #pragma unroll
                for (int ni = 0; ni < 4; ni++)
                    acc[mi][ni] = __builtin_amdgcn_mfma_f32_16x16x32_bf16(af[mi], bfr[ni], acc[mi][ni], 0, 0, 0);
        }
        __syncthreads();
    }
    #pragma unroll
    for (int ni = 0; ni < 4; ni++) {
        const int o = o0 + wnO + ni * 16 + l15;
        #pragma unroll
        for (int mi = 0; mi < 4; mi++) {
            const int c = c0 + wmC + mi * 16 + quad * 4;
            union { unsigned short s[4]; uint2 u; } p;
            #pragma unroll
            for (int rr = 0; rr < 4; rr++) p.s[rr] = f2bf(acc[mi][ni][rr]);
            *(uint2*)(Weff + ((size_t)bz * 256 + o) * 256 + c) = p.u;
        }
    }
}

// ---------------- K6: y = Weff @ x + b_out (C^T: M=n, N=o), BK=64 swizzled ----------
__global__ __launch_bounds__(256) void k_y(const unsigned short* __restrict__ Weff,
                                           const unsigned short* __restrict__ xT,
                                           const float* __restrict__ b_out,
                                           float* __restrict__ y) {
    __shared__ __align__(16) unsigned short As[128 * 64];   // n-rows (xT)
    __shared__ __align__(16) unsigned short Bs[128 * 64];   // o-rows (Weff)
    const int t = threadIdx.x;
    const int o0 = blockIdx.x * 128;
    const int n0 = blockIdx.y * 128;
    const int bz = blockIdx.z;
    const int lane = t & 63, wv = t >> 6, quad = lane >> 4, l15 = lane & 15;
    const int wmN = (wv & 1) * 64, wnO = (wv >> 1) * 64;

    const int srow8 = lane >> 3, sslot = lane & 7;
    const int scol = ((sslot - srow8) & 7) * 8;
    const int sw0 = ((quad + l15) & 7) * 8;

    const unsigned short* Ag = xT + ((size_t)bz * NSP + n0 + wv * 32 + srow8) * CIN + scol;
    const unsigned short* Bg = Weff + ((size_t)bz * 256 + o0 + wv * 32 + srow8) * CIN + scol;
    unsigned short* Al = As + wv * 32 * 64;
    unsigned short* Bl = Bs + wv * 32 * 64;

    v4f acc[4][4];
    #pragma unroll
    for (int i = 0; i < 4; i++)
        #pragma unroll
        for (int j = 0; j < 4; j++) acc[i][j] = (v4f)0.f;

    for (int kk = 0; kk < CIN; kk += 64) {
        #pragma unroll
        for (int cc = 0; cc < 4; cc++) {
            gld_lds16(Ag + (size_t)(cc * 8) * CIN + kk, Al + cc * 8 * 64);
            gld_lds16(Bg + (size_t)(cc * 8) * CIN + kk, Bl + cc * 8 * 64);
        }
        __syncthreads();
        #pragma unroll
        for (int h = 0; h < 2; h++) {
            const int sw = sw0 ^ (h * 32);
            v8s af[4], bfr[4];
            #pragma unroll
            for (int mi = 0; mi < 4; mi++) {
                union { v8s v; uint4 u; } rr;
                rr.u = *(const uint4*)(&As[(wmN + mi * 16 + l15) * 64 + sw]);
                af[mi] = rr.v;
            }
            #pragma unroll
            for (int ni = 0; ni < 4; ni++) {
                union { v8s v; uint4 u; } rr;
                rr.u = *(const uint4*)(&Bs[(wnO + ni * 16 + l15) * 64 + sw]);
                bfr[ni] = rr.v;
            }
            #pragma unroll
            for (int mi = 0; mi < 4; mi++)
                #pragma unroll
                for (int ni = 0; ni < 4; ni++)
                    acc[mi][ni] = __builtin_amdgcn_mfma_f32_16x16x32_bf16(af[mi], bfr[ni], acc[mi][ni], 0, 0, 0);
        }
        __syncthreads();
    }
    #pragma unroll
    for (int ni = 0; ni < 4; ni++) {
        const int o = o0 + wnO + ni * 16 + l15;
        const float bias = b_out[o];
        #pragma unroll
        for (int mi = 0; mi < 4; mi++) {
            const int n = n0 + wmN + mi * 16 + quad * 4;
            v4f v = acc[mi][ni];
            v[0] += bias; v[1] += bias; v[2] += bias; v[3] += bias;
            *(v4f*)(y + ((size_t)bz * 256 + o) * NSP + n) = v;
        }
    }
}

extern "C" void kernel_launch(void* const* d_in, const int* in_sizes, int n_in,
                              void* d_out, int out_size, void* d_ws, size_t ws_size,
                              hipStream_t stream) {
    (void)in_sizes; (void)n_in; (void)out_size; (void)ws_size;
    const float* x     = (const float*)d_in[0];
    const float* w_qkv = (const float*)d_in[1];
    const float* w_out = (const float*)d_in[2];
    const float* b_out = (const float*)d_in[3];
    float* y = (float*)d_out;
    char* ws = (char*)d_ws;

    unsigned short* xT   = (unsigned short*)(ws);                 //  33,554,432 B
    unsigned short* xbf  = (unsigned short*)(ws + 33554432);      //  33,554,432 B
    unsigned short* Spb  = (unsigned short*)(ws + 67108864);      //  16,777,216 B (bf16)
    float*          zacc = (float*)(ws + 83886080);               //      32,768 B
    unsigned short* Wc   = (unsigned short*)(ws + 83918848);      //   4,194,304 B
    unsigned short* Weff = (unsigned short*)(ws + 88113152);      //   2,097,152 B
    unsigned short* wbf  = (unsigned short*)(ws + 90210304);      //     786,432 B
    unsigned short* wqT  = (unsigned short*)(ws + 90996736);      //     524,288 B

    k_prep <<<dim3(4352),       256, 0, stream>>>(x, w_qkv, xbf, xT, wbf, wqT, zacc);
    k_ks   <<<dim3(256),        512, 0, stream>>>(wbf, xT, xbf, Spb, zacc);
    k_redwc<<<dim3(64),         256, 0, stream>>>(Spb, zacc, wbf, w_out, Wc);
    k_chain<<<dim3(2, 2, 16),   256, 0, stream>>>(Wc, wqT, Weff);
    k_y    <<<dim3(2, 32, 16),  256, 0, stream>>>(Weff, xT, b_out, y);
}